// Round 1
// 254.036 us; speedup vs baseline: 1.0409x; 1.0409x over previous
//
#include <hip/hip_runtime.h>

// ---------------------------------------------------------------------------
// AttnBlock: GroupNorm -> QKV (1x1 conv) -> 4-head attention (L=2048, hd=128)
//            -> out proj -> residual.   B=8, C=512, L=2048, G=4, NH=4.
// Storage dtype: float32. Internal compute: bf16 MFMA, f32 accumulation.
// R12: T12 in-register P. R11's attn round-tripped P through LDS (8 u64
//      writes + 4 b128 reads/iter/wave) just to relayout S^T regs into the
//      PV B-operand. That relayout is exactly one half<->half exchange:
//      v_cvt_pk_bf16_f32 pairs + v_permlane32_swap_b32. Removes 12 LDS
//      ops/iter (44->32, LDS pipe is the measured bottleneck at ~65% busy),
//      drops barrier #2 (3->2 barriers/iter: single vm<=8 wait covers K+V),
//      and halves the pack VALU. Other kernels unchanged from R10/R11.
// ---------------------------------------------------------------------------

typedef unsigned short u16;
typedef unsigned int   u32;
typedef unsigned long long u64;
typedef __attribute__((ext_vector_type(8)))  short          bf16x8;  // MFMA A/B frag
typedef __attribute__((ext_vector_type(4)))  float          f32x4;   // 16x16 C/D
typedef __attribute__((ext_vector_type(16))) float          f32x16;  // 32x32 C/D
typedef __attribute__((ext_vector_type(4)))  unsigned int   u32x4;
typedef __attribute__((ext_vector_type(8)))  unsigned short u16x8;

#define MFMA16(a, b, c) __builtin_amdgcn_mfma_f32_16x16x32_bf16((a), (b), (c), 0, 0, 0)
#define MFMA32(a, b, c) __builtin_amdgcn_mfma_f32_32x32x16_bf16((a), (b), (c), 0, 0, 0)

// s_waitcnt simm16: vmcnt[3:0]+[15:14], expcnt[6:4], lgkmcnt[13:8]
#define WAIT_VM8        16248   // vm<=8, lgkm untouched (0x3F78)
#define WAIT_LGKM0      49279   // lgkm=0, vm untouched (0xC07F)
#define BARRIER() __builtin_amdgcn_s_barrier()

__device__ __forceinline__ u16 f2bf(float f) {
    union { float f; unsigned int i; } cv;
    cv.f = f;
    unsigned int u = cv.i;
    u += 0x7fffu + ((u >> 16) & 1);   // RNE
    return (u16)(u >> 16);
}
__device__ __forceinline__ u32 fbits(float f) {
    union { float f; unsigned int i; } cv; cv.f = f; return cv.i;
}

// pack two f32 -> {lo,hi} bf16 in one instr (RNE)
__device__ __forceinline__ u32 cvtpk_bf16(float lo, float hi) {
    u32 d;
    asm("v_cvt_pk_bf16_f32 %0, %1, %2" : "=v"(d) : "v"(lo), "v"(hi));
    return d;
}
// a[32:63] <-> b[0:31]. Post: a = {a_lo, b_lo_from_lane-32}; b = {a_hi_from_lane+32, b_hi}
__device__ __forceinline__ void permswap(u32& a, u32& b) {
    asm("v_permlane32_swap_b32 %0, %1" : "+v"(a), "+v"(b));
}

// async 16B global->LDS (DMA; lands at lds_base + lane*16)
__device__ __forceinline__ void async16(const u16* g, u16* l) {
    __builtin_amdgcn_global_load_lds(
        (const __attribute__((address_space(1))) unsigned int*)g,
        (__attribute__((address_space(3))) unsigned int*)l, 16, 0, 0);
}

#define BATCH 8
#define CCH   512
#define LEN   2048
#define NGRP  4
#define NHEAD 4
#define HD    128
#define GSIZE (128 * 2048)   // elements per (b, group)

// ---------------------------------------------------------------------------
// 0) Fused prep: blocks 0..255 = GroupNorm partial stats; 256..767 = weight
//    conversion (4 x 512x512 f32 -> bf16). Independent work, one dispatch.
// ---------------------------------------------------------------------------
__global__ __launch_bounds__(256) void prep_k(const float* __restrict__ x,
                                              float* __restrict__ stats,
                                              const float* __restrict__ w0,
                                              const float* __restrict__ w1,
                                              const float* __restrict__ w2,
                                              const float* __restrict__ w3,
                                              u16* __restrict__ dst) {
    const int bid = blockIdx.x;
    if (bid < 256) {
        const int grp   = bid >> 3;         // b*4+g
        const int chunk = bid & 7;
        const int b = grp >> 2, g = grp & 3;
        const float* base = x + ((size_t)(b * CCH + g * 128 + chunk * 16)) * LEN;

        float s = 0.f, ss = 0.f;
        for (int i = 0; i < 32; ++i) {
            int cid = threadIdx.x + i * 256;
            f32x4 dv = *(const f32x4*)(base + (size_t)cid * 4);
            for (int u = 0; u < 4; ++u) { s += dv[u]; ss += dv[u] * dv[u]; }
        }
        for (int m = 1; m < 64; m <<= 1) {
            s  += __shfl_xor(s,  m, 64);
            ss += __shfl_xor(ss, m, 64);
        }
        __shared__ float red[8];
        int wid = threadIdx.x >> 6, lane = threadIdx.x & 63;
        if (lane == 0) { red[wid * 2] = s; red[wid * 2 + 1] = ss; }
        __syncthreads();
        if (threadIdx.x == 0) {
            float ts  = red[0] + red[2] + red[4] + red[6];
            float tss = red[1] + red[3] + red[5] + red[7];
            atomicAdd(&stats[grp * 2],     ts);
            atomicAdd(&stats[grp * 2 + 1], tss);
        }
    } else {
        const int wb = bid - 256;           // 0..511
        const int mat = wb >> 7, chunk = wb & 127;
        const float* src = (mat == 0) ? w0 : (mat == 1) ? w1 : (mat == 2) ? w2 : w3;
        const size_t base = (size_t)chunk * 2048 + (size_t)threadIdx.x * 8;
        f32x4 a = *(const f32x4*)(src + base);
        f32x4 b2 = *(const f32x4*)(src + base + 4);
        u16x8 o;
        for (int u = 0; u < 4; ++u) { o[u] = f2bf(a[u]); o[u + 4] = f2bf(b2[u]); }
        *(u16x8*)(dst + (size_t)mat * 262144 + base) = o;
    }
}

// ---------------------------------------------------------------------------
// 1) GroupNorm apply + transpose: x[b,c,l] (f32) -> hT[b,l,c] (bf16).
// ---------------------------------------------------------------------------
__global__ __launch_bounds__(256) void gn_apply_k(const float* __restrict__ x,
                                                  const float* __restrict__ gns,
                                                  const float* __restrict__ gnb,
                                                  const float* __restrict__ stats,
                                                  u16* __restrict__ hT) {
    __shared__ u16 Ts[64 * 72];
    const int b = blockIdx.z, c0 = blockIdx.y * 64, l0 = blockIdx.x * 64;
    const int g = c0 >> 7;
    const int tid = threadIdx.x;

    float sum   = stats[(b * NGRP + g) * 2];
    float sumsq = stats[(b * NGRP + g) * 2 + 1];
    const float invN = 1.f / (float)GSIZE;
    float mean = sum * invN;
    float var  = sumsq * invN - mean * mean;
    float rstd = rsqrtf(var + 1e-6f);

    for (int i = 0; i < 4; ++i) {
        int cid = tid + i * 256;
        int row = cid >> 4, c4 = cid & 15;
        int c = c0 + row;
        float sc = gns[c] * rstd;
        float bi = gnb[c] - mean * sc;
        f32x4 dv = *(const f32x4*)(x + ((size_t)(b * CCH + c)) * LEN + l0 + c4 * 4);
        for (int u = 0; u < 4; ++u)
            Ts[row * 72 + c4 * 4 + u] = f2bf(dv[u] * sc + bi);
    }
    __syncthreads();
    for (int i = 0; i < 2; ++i) {
        int cid = tid + i * 256;
        int lrow = cid >> 3, c8 = cid & 7;
        u16x8 ov;
        for (int u = 0; u < 8; ++u) ov[u] = Ts[(c8 * 8 + u) * 72 + lrow];
        *(u16x8*)(hT + ((size_t)b * LEN + l0 + lrow) * CCH + c0 + c8 * 8) = ov;
    }
}

// ---------------------------------------------------------------------------
// 2) Fused QKV GEMM (mode0 = qT/kT, mode1 = v), dbuf K-loop. Unchanged R10.
// ---------------------------------------------------------------------------
__global__ __launch_bounds__(256, 2) void gemm01_k(const u16* __restrict__ hT,
                                                   const u16* __restrict__ wq_bf,
                                                   const u16* __restrict__ wk_bf,
                                                   const u16* __restrict__ wv_bf,
                                                   const float* __restrict__ bq,
                                                   const float* __restrict__ bk,
                                                   const float* __restrict__ bv,
                                                   u16* __restrict__ qT,
                                                   u16* __restrict__ kT,
                                                   u16* __restrict__ vbuf) {
    __shared__ u16 As[2][128 * 64];
    __shared__ u16 Bs[2][128 * 64];
    const int bid = blockIdx.x;
    const bool mode0 = (bid < 1024);
    int b, m0, n0;
    const u16 *Arow, *Brow;
    if (mode0) {
        b = bid >> 7; m0 = ((bid >> 3) & 15) * 128; n0 = (bid & 7) * 128;
        Arow = hT + ((size_t)b * LEN + m0) * 512;
        Brow = (n0 < 512) ? (wq_bf + (size_t)n0 * 512)
                          : (wk_bf + (size_t)(n0 - 512) * 512);
    } else {
        int bid2 = bid - 1024;
        b = bid2 >> 6; m0 = ((bid2 >> 4) & 3) * 128; n0 = (bid2 & 15) * 128;
        Arow = wv_bf + (size_t)m0 * 512;
        Brow = hT + ((size_t)b * LEN + n0) * 512;
    }

    const int tid = threadIdx.x;
    const int lane = tid & 63, wid = tid >> 6;
    const int quad = lane >> 4, l15 = lane & 15;
    const int wm = (wid & 1) * 64, wn = (wid >> 1) * 64;

    f32x4 acc[4][4] = {};
    const int srl = lane >> 3, scl = lane & 7;

#pragma unroll
    for (int i = 0; i < 4; ++i) {
        int rloc = wid * 32 + i * 8 + srl;
        int lc = scl ^ (rloc & 7);
        async16(Arow + (size_t)rloc * 512 + lc * 8, &As[0][(wid * 32 + i * 8) * 64]);
        async16(Brow + (size_t)rloc * 512 + lc * 8, &Bs[0][(wid * 32 + i * 8) * 64]);
    }
    __syncthreads();

    for (int kk = 0; kk < 8; ++kk) {
        const int p = kk & 1;
        if (kk < 7) {
            const int k0n = (kk + 1) * 64;
#pragma unroll
            for (int i = 0; i < 4; ++i) {
                int rloc = wid * 32 + i * 8 + srl;
                int lc = scl ^ (rloc & 7);
                async16(Arow + (size_t)rloc * 512 + k0n + lc * 8,
                        &As[1 - p][(wid * 32 + i * 8) * 64]);
                async16(Brow + (size_t)rloc * 512 + k0n + lc * 8,
                        &Bs[1 - p][(wid * 32 + i * 8) * 64]);
            }
        }
#pragma unroll
        for (int ks = 0; ks < 2; ++ks) {
            bf16x8 af[4], bfr[4];
            for (int t = 0; t < 4; ++t) {
                int ra = wm + t * 16 + l15, rb = wn + t * 16 + l15;
                af[t]  = *(const bf16x8*)(&As[p][ra * 64 + (((ks * 4 + quad) ^ (ra & 7))) * 8]);
                bfr[t] = *(const bf16x8*)(&Bs[p][rb * 64 + (((ks * 4 + quad) ^ (rb & 7))) * 8]);
            }
            for (int mt = 0; mt < 4; ++mt)
                for (int nt = 0; nt < 4; ++nt)
                    acc[mt][nt] = MFMA16(af[mt], bfr[nt], acc[mt][nt]);
        }
        __syncthreads();
    }

    if (mode0) {
        const int col0 = (n0 < 512) ? n0 : n0 - 512;
        const float* biasp = ((n0 < 512) ? bq : bk) + col0;
        u16* outp = (n0 < 512) ? qT : kT;
        for (int nt = 0; nt < 4; ++nt) {
            int nl = wn + nt * 16 + l15;
            float bv_ = biasp[nl];
            for (int mt = 0; mt < 4; ++mt)
                for (int r = 0; r < 4; ++r) {
                    int ml = wm + mt * 16 + quad * 4 + r;
                    size_t idx = ((size_t)b * LEN + m0 + ml) * 512 + col0 + nl;
                    outp[idx] = f2bf(acc[mt][nt][r] + bv_);
                }
        }
    } else {
        for (int mt = 0; mt < 4; ++mt)
            for (int r = 0; r < 4; ++r) {
                int ml = wm + mt * 16 + quad * 4 + r;
                float bv_ = bv[m0 + ml];
                for (int nt = 0; nt < 4; ++nt) {
                    int nl = wn + nt * 16 + l15;
                    size_t idx = ((size_t)(b * 512 + m0 + ml)) * LEN + n0 + nl;
                    vbuf[idx] = f2bf(acc[mt][nt][r] + bv_);
                }
            }
    }
}

// ---------------------------------------------------------------------------
// 3) GEMM MODE 2 (out-proj + residual). Unchanged R10.
// ---------------------------------------------------------------------------
__global__ __launch_bounds__(256, 2) void gemm2_k(const u16* __restrict__ A0,
                                                  const u16* __restrict__ B0,
                                                  const float* __restrict__ bias0,
                                                  const float* __restrict__ resid,
                                                  float* __restrict__ out0) {
    __shared__ u16 As[2][128 * 64];
    __shared__ u16 Bs[2][128 * 64];
    const int b  = blockIdx.z;
    const int n0 = blockIdx.x * 128;
    const int m0 = blockIdx.y * 128;
    const int tid = threadIdx.x;
    const int lane = tid & 63, wid = tid >> 6;
    const int quad = lane >> 4, l15 = lane & 15;
    const int wm = (wid & 1) * 64, wn = (wid >> 1) * 64;

    const u16* Arow = A0 + (size_t)m0 * 512;
    const u16* Brow = B0 + ((size_t)b * LEN + n0) * 512;

    f32x4 acc[4][4] = {};
    const int srl = lane >> 3, scl = lane & 7;

#pragma unroll
    for (int i = 0; i < 4; ++i) {
        int rloc = wid * 32 + i * 8 + srl;
        int lc = scl ^ (rloc & 7);
        async16(Arow + (size_t)rloc * 512 + lc * 8, &As[0][(wid * 32 + i * 8) * 64]);
        async16(Brow + (size_t)rloc * 512 + lc * 8, &Bs[0][(wid * 32 + i * 8) * 64]);
    }
    __syncthreads();

    for (int kk = 0; kk < 8; ++kk) {
        const int p = kk & 1;
        if (kk < 7) {
            const int k0n = (kk + 1) * 64;
#pragma unroll
            for (int i = 0; i < 4; ++i) {
                int rloc = wid * 32 + i * 8 + srl;
                int lc = scl ^ (rloc & 7);
                async16(Arow + (size_t)rloc * 512 + k0n + lc * 8,
                        &As[1 - p][(wid * 32 + i * 8) * 64]);
                async16(Brow + (size_t)rloc * 512 + k0n + lc * 8,
                        &Bs[1 - p][(wid * 32 + i * 8) * 64]);
            }
        }
#pragma unroll
        for (int ks = 0; ks < 2; ++ks) {
            bf16x8 af[4], bfr[4];
            for (int t = 0; t < 4; ++t) {
                int ra = wm + t * 16 + l15, rb = wn + t * 16 + l15;
                af[t]  = *(const bf16x8*)(&As[p][ra * 64 + (((ks * 4 + quad) ^ (ra & 7))) * 8]);
                bfr[t] = *(const bf16x8*)(&Bs[p][rb * 64 + (((ks * 4 + quad) ^ (rb & 7))) * 8]);
            }
            for (int mt = 0; mt < 4; ++mt)
                for (int nt = 0; nt < 4; ++nt)
                    acc[mt][nt] = MFMA16(af[mt], bfr[nt], acc[mt][nt]);
        }
        __syncthreads();
    }

    for (int mt = 0; mt < 4; ++mt)
        for (int r = 0; r < 4; ++r) {
            int ml = wm + mt * 16 + quad * 4 + r;
            float bv_ = bias0[m0 + ml];
            for (int nt = 0; nt < 4; ++nt) {
                int nl = wn + nt * 16 + l15;
                size_t idx = ((size_t)(b * 512 + m0 + ml)) * LEN + n0 + nl;
                out0[idx] = acc[mt][nt][r] + bv_ + resid[idx];
            }
        }
}

// ---------------------------------------------------------------------------
// 4) Flash attention v12: 32x32x16 MFMA, in-register P (T12).
// 256 threads, 4 waves, wave owns 32 q-rows (m = lane&31 -> softmax & rescale
// lane-local). Q-tile 128, j-tile 64, 32 iters. LDS: Ks[2][64x128] +
// Vs[2][128x64] = 64KB. 16B-unit XOR swizzle on K/V.
// Per iter: issue K(jt+1)x4 + V(jt+1)x4 DMA; vm<=8 (K+V of jt landed);
// barrier; QK (2 S^T tiles x 8 MFMA, A=K LDS, B=Q regs); lane-local softmax;
// cvt_pk+permlane32_swap pack P into B-frags in-register (no LDS round-trip);
// PV (A=V LDS, B=P regs; 16 reads, 16 MFMA); lgkm0; barrier.
// S^T reg layout: lane m=l31; (t,g,q,half) -> j = t*32 + g*8 + 4*half + q.
// PV B-frag needs: lane (l31,h): e=0..7 -> j = jb*16 + 8h + e. With g=2u+h,
// e=4*h_src+q: permswap(A_2u,A_2u+1) yields words {e0e1, e4e5} for both
// halves; same with B_g for {e2e3, e6e7}. Bit-identical to R11's LDS P path.
// XCD swizzle: xcd=bid&7 owns one batch's 4 heads.
// ---------------------------------------------------------------------------
__global__ __launch_bounds__(256, 2) void attn_k(const u16* __restrict__ qT,
                                                 const u16* __restrict__ kT,
                                                 const u16* __restrict__ v,
                                                 u16* __restrict__ attnT) {
    __shared__ u16 Ks[2][64 * 128];
    __shared__ u16 Vs[2][128 * 64];
    const int bid = blockIdx.x;
    const int xcd = bid & 7, slot = bid >> 3;      // 64 slots per XCD
    const int bh  = xcd * 4 + (slot >> 4);
    const int qt  = slot & 15;
    const int b = bh >> 2, h = bh & 3;
    const int i0 = qt * 128;

    const int tid = threadIdx.x, lane = tid & 63, wg = tid >> 6;   // wg 0..3
    const int l31 = lane & 31, half = lane >> 5;
    const int mrow = wg * 32 + l31;    // this lane's q-row within the 128-tile

    // Q B-frags: B[k=d][n=m], lane n=l31, k = ks*16 + half*8 + e
    bf16x8 qa[8];
#pragma unroll
    for (int ks = 0; ks < 8; ++ks)
        qa[ks] = *(const bf16x8*)(qT + ((size_t)b * LEN + i0 + mrow) * 512 + h * HD +
                                  ks * 16 + half * 8);

    float mst = -3.0e38f, lst = 0.f;   // per-lane (m = l31), half-replicated
    f32x16 oacc[4] = {};               // O^T[d][m]: 4 d-tiles of 32

    const float SL2E = 0.08838834764831845f * 1.4426950408889634f; // scale*log2e

    // DMA staging: K 4 instr (4 rows x 16 units each), V 4 instr (8 rows x 8)
    const u16* kbase = kT + ((size_t)b * LEN) * 512 + h * HD;
    const u16* vbase = v + ((size_t)(b * CCH + h * HD)) * LEN;
    const u16* kgp[4];
    const u16* vgp[4];
    int krow[4], vrow[4];
#pragma unroll
    for (int i = 0; i < 4; ++i) {
        int rk = wg * 16 + i * 4 + (lane >> 4);
        krow[i] = wg * 16 + i * 4;
        kgp[i] = kbase + (size_t)rk * 512 + ((lane & 15) ^ (rk & 7)) * 8;
        int rv = wg * 32 + i * 8 + (lane >> 3);
        vrow[i] = wg * 32 + i * 8;
        vgp[i] = vbase + (size_t)rv * LEN + ((lane & 7) ^ (rv & 7)) * 8;
    }

    // prologue: stage tile 0 into buffer 0, advance to tile 1
#pragma unroll
    for (int i = 0; i < 4; ++i) {
        async16(kgp[i], &Ks[0][krow[i] * 128]);
        async16(vgp[i], &Vs[0][vrow[i] * 64]);
        kgp[i] += 64 * 512;
        vgp[i] += 64;
    }

    for (int jt = 0; jt < 32; ++jt) {
        const int p = jt & 1;

        // issue next tile's DMA into [1-p] (jt=31: harmless re-stage)
#pragma unroll
        for (int i = 0; i < 4; ++i) async16(kgp[i], &Ks[1 - p][krow[i] * 128]);
#pragma unroll
        for (int i = 0; i < 4; ++i) async16(vgp[i], &Vs[1 - p][vrow[i] * 64]);
        if (jt < 30) {
#pragma unroll
            for (int i = 0; i < 4; ++i) { kgp[i] += 64 * 512; vgp[i] += 64; }
        }

        __builtin_amdgcn_s_waitcnt(WAIT_VM8);    // K(jt)+V(jt) landed (mine)
        BARRIER();                               // landed for all waves

        // QK: S^T tiles t=0,1 (j rows t*32.., m cols). A=K frag, B=Q regs.
        f32x16 st[2] = {};
#pragma unroll
        for (int t = 0; t < 2; ++t) {
            int r = t * 32 + l31;
#pragma unroll
            for (int ks = 0; ks < 8; ++ks) {
                bf16x8 kf = *(const bf16x8*)(&Ks[p][r * 128 + ((ks * 2 + half) ^ (r & 7)) * 8]);
                st[t] = MFMA32(kf, qa[ks], st[t]);
            }
        }

        // lane-local online softmax (m = l31; halves hold disjoint j sets)
        float rm = -3.0e38f;
#pragma unroll
        for (int t = 0; t < 2; ++t)
            for (int r = 0; r < 16; ++r) rm = fmaxf(rm, st[t][r]);
        rm *= SL2E;
        rm = fmaxf(rm, __shfl_xor(rm, 32, 64));
        float mnew  = fmaxf(mst, rm);
        float alpha = __builtin_amdgcn_exp2f(mst - mnew);
        mst = mnew;
        float rs = 0.f;
#pragma unroll
        for (int t = 0; t < 2; ++t)
            for (int r = 0; r < 16; ++r) {
                float pv_ = __builtin_amdgcn_exp2f(st[t][r] * SL2E - mnew);
                st[t][r] = pv_;
                rs += pv_;
            }
        rs += __shfl_xor(rs, 32, 64);
        lst = lst * alpha + rs;
        if (__ballot(alpha != 1.0f) != 0ull) {
#pragma unroll
            for (int dt = 0; dt < 4; ++dt)
                for (int r = 0; r < 16; ++r) oacc[dt][r] *= alpha;
        }

        // T12: pack P into PV B-frags fully in-register.
        // A_g = pk(q0,q1), B_g = pk(q2,q3); permswap pairs (g=2u, 2u+1).
        u32 pw[4][4];
#pragma unroll
        for (int t = 0; t < 2; ++t) {
            u32 Ag[4], Bg[4];
#pragma unroll
            for (int g = 0; g < 4; ++g) {
                Ag[g] = cvtpk_bf16(st[t][g * 4 + 0], st[t][g * 4 + 1]);
                Bg[g] = cvtpk_bf16(st[t][g * 4 + 2], st[t][g * 4 + 3]);
            }
#pragma unroll
            for (int u = 0; u < 2; ++u) {
                u32 a0 = Ag[2 * u], a1 = Ag[2 * u + 1];
                u32 b0 = Bg[2 * u], b1 = Bg[2 * u + 1];
                permswap(a0, a1);     // a0={e0,e1}, a1={e4,e5} (both halves)
                permswap(b0, b1);     // b0={e2,e3}, b1={e6,e7}
                const int jb = t * 2 + u;
                pw[jb][0] = a0; pw[jb][1] = b0; pw[jb][2] = a1; pw[jb][3] = b1;
            }
        }

        // PV: O^T[d][m] += V[d][j] * P[m][j]. A=V frag (LDS), B=P frag (regs).
#pragma unroll
        for (int jb = 0; jb < 4; ++jb) {
            union { u32 w[4]; bf16x8 v8; } pu_;
            pu_.w[0] = pw[jb][0]; pu_.w[1] = pw[jb][1];
            pu_.w[2] = pw[jb][2]; pu_.w[3] = pw[jb][3];
#pragma unroll
            for (int dt = 0; dt < 4; ++dt) {
                int d = dt * 32 + l31;
                bf16x8 vf = *(const bf16x8*)(&Vs[p][d * 64 + ((jb * 2 + half) ^ (d & 7)) * 8]);
                oacc[dt] = MFMA32(vf, pu_.v8, oacc[dt]);
            }
        }

        __builtin_amdgcn_s_waitcnt(WAIT_LGKM0);  // my K/V LDS reads retired
        BARRIER();                               // [p] free for jt+1's re-DMA
    }

    // epilogue: O[m][d] = oacc/lst. d = dt*32 + g*8 + half*4 + (r&3)
    float inv = 1.f / lst;
    for (int dt = 0; dt < 4; ++dt)
        for (int g = 0; g < 4; ++g) {
            u64 w =  (u64)f2bf(oacc[dt][g * 4 + 0] * inv)
                  | ((u64)f2bf(oacc[dt][g * 4 + 1] * inv) << 16)
                  | ((u64)f2bf(oacc[dt][g * 4 + 2] * inv) << 32)
                  | ((u64)f2bf(oacc[dt][g * 4 + 3] * inv) << 48);
            int c = h * HD + dt * 32 + g * 8 + half * 4;
            *(u64*)(attnT + ((size_t)b * LEN + i0 + mrow) * 512 + c) = w;
        }
}

// ---------------------------------------------------------------------------
extern "C" void kernel_launch(void* const* d_in, const int* in_sizes, int n_in,
                              void* d_out, int out_size, void* d_ws, size_t ws_size,
                              hipStream_t stream) {
    const float* x   = (const float*)d_in[0];
    const float* gns = (const float*)d_in[1];
    const float* gnb = (const float*)d_in[2];
    const float* wq  = (const float*)d_in[3];
    const float* bq  = (const float*)d_in[4];
    const float* wk  = (const float*)d_in[5];
    const float* bk  = (const float*)d_in[6];
    const float* wv  = (const float*)d_in[7];
    const float* bv  = (const float*)d_in[8];
    const float* wo  = (const float*)d_in[9];
    const float* bo  = (const float*)d_in[10];
    float* out = (float*)d_out;

    const size_t NEL = (size_t)BATCH * CCH * LEN;   // 8388608
    float* stats = (float*)d_ws;                     // 64 floats @ 0
    u16* wcat  = (u16*)((char*)d_ws + 256);          // 4 x 512x512 bf16 weights
    u16* hT    = wcat + 4 * 262144;                  // bf16 [B,L,C]; reused as attnT
    u16* qT    = hT + NEL;
    u16* kT    = qT + NEL;
    u16* vbuf  = kT + NEL;
    u16* attnT = hT;   // hT dead after gemm01; alias

    const u16* wq_bf = wcat;
    const u16* wk_bf = wcat + 262144;
    const u16* wv_bf = wcat + 2 * 262144;
    const u16* wo_bf = wcat + 3 * 262144;

    hipMemsetAsync(d_ws, 0, 256, stream);
    prep_k<<<768, 256, 0, stream>>>(x, stats, wq, wk, wv, wo, wcat);
    gn_apply_k<<<dim3(32, 8, 8), 256, 0, stream>>>(x, gns, gnb, stats, hT);
    gemm01_k<<<1536, 256, 0, stream>>>(hT, wq_bf, wk_bf, wv_bf, bq, bk, bv, qT, kT, vbuf);
    attn_k<<<512, 256, 0, stream>>>(qT, kT, vbuf, attnT);
    gemm2_k<<<dim3(16, 4, 8), 256, 0, stream>>>(wo_bf, attnT, bo, x, out);
}